// Round 1
// 93.681 us; speedup vs baseline: 1.1102x; 1.1102x over previous
//
#include <hip/hip_runtime.h>
#include <math.h>

// ---------------------------------------------------------------------------
// Types for MFMA fragments (guide §3: bf16 16x16x32 -> 8 bf16 in, 4 f32 out)
// ---------------------------------------------------------------------------
typedef __attribute__((ext_vector_type(8))) short short8;
typedef __attribute__((ext_vector_type(4))) float floatx4;

__device__ __forceinline__ unsigned short f2bf(float f) {
    unsigned int u = __builtin_bit_cast(unsigned int, f);
    u += 0x7FFFu + ((u >> 16) & 1u);   // round-to-nearest-even
    return (unsigned short)(u >> 16);
}

// ---------------------------------------------------------------------------
// ws layout:
//   Wallb bf16 [1536][512]  (Wq rows 0-511, Wk 512-1023, Wv 1024-1535)
//   xb    bf16 [512][512]   (x, [t][d])
//   Wob   bf16 [512][512]   ([o][d])
//   attTb bf16 [512][512]   ([t][d])  <- written directly by attn_rope now
//   qkvf  f32  [1536][512]  ([o'][t]; q rows 0-511, k 512-1023, v 1024-1535)
// ---------------------------------------------------------------------------

// ---------------------------------------------------------------------------
// Kernel 1: fp32 -> bf16 conversion for x, Wq, Wk, Wv, Wo (pure elementwise).
// grid (256, 5), block 256; each thread converts 4 elements.
// ---------------------------------------------------------------------------
__global__ __launch_bounds__(256) void cvt_bf16(
    const float* __restrict__ x,  const float* __restrict__ Wq,
    const float* __restrict__ Wk, const float* __restrict__ Wv,
    const float* __restrict__ Wo, unsigned short* __restrict__ Wallb,
    unsigned short* __restrict__ xb, unsigned short* __restrict__ Wob)
{
    const float* src; unsigned short* dst;
    switch (blockIdx.y) {
        case 0: src = Wq; dst = Wallb;          break;
        case 1: src = Wk; dst = Wallb + 262144; break;
        case 2: src = Wv; dst = Wallb + 524288; break;
        case 3: src = x;  dst = xb;             break;
        default: src = Wo; dst = Wob;           break;
    }
    const int i4 = (blockIdx.x * 256 + threadIdx.x) * 4;
    const float4 v = *(const float4*)(src + i4);
    ushort4 o;
    o.x = f2bf(v.x); o.y = f2bf(v.y); o.z = f2bf(v.z); o.w = f2bf(v.w);
    *(ushort4*)(dst + i4) = o;
}

// ---------------------------------------------------------------------------
// Kernel 2/4: bf16 MFMA GEMM, C[m][n] = sum_k A[m][k]*B[n][k] (both k-contig).
// K = 512 fixed, ldc = 512 fixed. Block 256 thr = 4 waves; 64x64 block tile;
// wave tile 32x32 = 2x2 mfma_f32_16x16x32_bf16 tiles. BK=64,
// global_load_lds width 16, XOR-swizzled k-chunks to avoid bank conflicts.
// NOW DOUBLE-BUFFERED: both launches run ~1 block/CU (192 resp. 64 blocks),
// so there is no inter-block overlap to hide the staging latency — prefetch
// tile k+1 while computing tile k, with counted vmcnt (guide §5 template):
//   stage(k+1) ; s_waitcnt vmcnt(4) ; s_barrier ; sched_barrier(0) ;
//   compute(k) ; s_barrier ; sched_barrier(0)
// sched_barrier(0) after each raw s_barrier pins ds_read / glds motion
// (guide rule 18: compiler can hoist past inline-asm waitcnt otherwise).
// ---------------------------------------------------------------------------
__global__ __launch_bounds__(256) void gemm_bt(
    const unsigned short* __restrict__ A,   // [M][512] bf16
    const unsigned short* __restrict__ B,   // [N][512] bf16
    float* __restrict__ C)                  // [M][512] f32
{
    __shared__ unsigned short As[2][64 * 64];
    __shared__ unsigned short Bs[2][64 * 64];

    const int tid  = threadIdx.x;
    const int lane = tid & 63;
    const int w    = tid >> 6;            // wave 0..3
    const int m0   = blockIdx.y * 64;
    const int n0   = blockIdx.x * 64;
    const int wm   = (w >> 1) * 32;
    const int wn   = (w & 1) * 32;

    const int srow8 = w * 8 + (lane >> 3);  // staging row within 32-row round
    const int c8    = lane & 7;             // 16B chunk index within 64-k row

    floatx4 acc[2][2] = {{{0.f,0.f,0.f,0.f},{0.f,0.f,0.f,0.f}},
                         {{0.f,0.f,0.f,0.f},{0.f,0.f,0.f,0.f}}};

    const int quad = lane >> 4;
    const int l15  = lane & 15;

    // 4 glds per wave per stage: rr{0,1} x {A,B}
    auto stage = [&](int kc, int buf) {
        #pragma unroll
        for (int rr = 0; rr < 2; ++rr) {
            const int row  = rr * 32 + srow8;           // 0..63
            const int gcol = kc + ((c8 ^ (row & 7)) * 8);
            const unsigned short* ga = A + (m0 + row) * 512 + gcol;
            const unsigned short* gb = B + (n0 + row) * 512 + gcol;
            __builtin_amdgcn_global_load_lds(
                (const __attribute__((address_space(1))) void*)ga,
                (__attribute__((address_space(3))) void*)&As[buf][(rr * 32 + w * 8) * 64],
                16, 0, 0);
            __builtin_amdgcn_global_load_lds(
                (const __attribute__((address_space(1))) void*)gb,
                (__attribute__((address_space(3))) void*)&Bs[buf][(rr * 32 + w * 8) * 64],
                16, 0, 0);
        }
    };

    stage(0, 0);                            // prologue: tile 0 -> buf 0

    #pragma unroll
    for (int kt = 0; kt < 8; ++kt) {
        const int cur = kt & 1;
        if (kt < 7) {
            stage((kt + 1) * 64, cur ^ 1);  // prefetch next tile
            // 8 outstanding glds; wait until only the 4 newest remain
            asm volatile("s_waitcnt vmcnt(4)" ::: "memory");
        } else {
            asm volatile("s_waitcnt vmcnt(0)" ::: "memory");
        }
        __builtin_amdgcn_s_barrier();
        __builtin_amdgcn_sched_barrier(0);  // keep ds_reads below the barrier

        #pragma unroll
        for (int ks = 0; ks < 2; ++ks) {
            const int cIdx = ks * 4 + quad;             // 16B chunk 0..7
            short8 a[2], b[2];
            #pragma unroll
            for (int mt = 0; mt < 2; ++mt) {
                const int row = wm + mt * 16 + l15;
                a[mt] = *(const short8*)&As[cur][row * 64 + ((cIdx ^ (row & 7)) * 8)];
            }
            #pragma unroll
            for (int nt = 0; nt < 2; ++nt) {
                const int row = wn + nt * 16 + l15;
                b[nt] = *(const short8*)&Bs[cur][row * 64 + ((cIdx ^ (row & 7)) * 8)];
            }
            #pragma unroll
            for (int mt = 0; mt < 2; ++mt)
                #pragma unroll
                for (int nt = 0; nt < 2; ++nt)
                    acc[mt][nt] = __builtin_amdgcn_mfma_f32_16x16x32_bf16(
                        a[mt], b[nt], acc[mt][nt], 0, 0, 0);
        }
        __builtin_amdgcn_s_barrier();
        __builtin_amdgcn_sched_barrier(0);  // keep next stage's glds below
    }

    // C/D layout (m89-verified): row = quad*4 + reg, col = lane&15
    #pragma unroll
    for (int mt = 0; mt < 2; ++mt)
        #pragma unroll
        for (int nt = 0; nt < 2; ++nt) {
            const int grow = m0 + wm + mt * 16 + quad * 4;
            const int gcol = n0 + wn + nt * 16 + l15;
            #pragma unroll
            for (int r = 0; r < 4; ++r)
                C[(grow + r) * 512 + gcol] = acc[mt][nt][r];
        }
}

// ---------------------------------------------------------------------------
// Kernel 3: fused RoPE + per-channel scalar causal attention (fp32),
// writing the transposed bf16 attention output attTb[t][ch] directly.
//
// Block = one channel ch (512 blocks), 256 threads. Thread t owns TWO
// queries: i1 = t and i2 = 511 - t, so every wave's weighted work is the
// uniform 576 j-steps (kills the old 1.3x wave-level triangle imbalance and
// the fully-masked tail). Scale 1/8 AND log2(e) are folded into k so the
// inner loop is a raw v_exp_f32 (exp2) — 4 VALU ops per (i,j) element.
//
// Phase structure (w = wave id 0..3, all bounds wave-uniform):
//   1a: j in [0, 64w)           : both queries, unmasked   (j <  i1 min)
//   1b: j in [64w, 64w+64)      : q1 masked (j<=i1), q2 unmasked (j<256<=i2)
//   2a: j in [64w+64, 448-64w)  : q2 only, unmasked        (j <  i2 min)
//   2b: j in [448-64w, 512-64w) : q2 masked (j<=i2)
// No max-subtraction: |q*k/8| <~ 3, exp cannot overflow; same math as ref.
// ---------------------------------------------------------------------------
__global__ __launch_bounds__(256) void attn_rope(
    const float* __restrict__ qkv, unsigned short* __restrict__ attTb)
{
    const int ch = blockIdx.x;
    const int t  = threadIdx.x;          // 0..255
    const int i1 = t;
    const int i2 = 511 - t;
    const int p  = ch ^ 256;
    const float sgn = (ch < 256) ? -1.f : 1.f;

    __shared__ float ks_[512];
    __shared__ float vs_[512];

    const float* __restrict__ qg = qkv;
    const float* __restrict__ kg = qkv + 262144;
    const float* __restrict__ vg = qkv + 524288;

    const float inv_freq = powf(10000.f, -(float)(ch & 31) * (1.f / 32.f));
    const float SC = 0.125f * 1.44269504088896f;  // 1/8 * log2(e) folded into k

    float sn_a, cs_a, sn_b, cs_b, sn_c, cs_c;
    sincosf((float)t * inv_freq,         &sn_a, &cs_a);   // pos t      (k + q1)
    sincosf((float)(t + 256) * inv_freq, &sn_b, &cs_b);   // pos t+256  (k)
    sincosf((float)i2 * inv_freq,        &sn_c, &cs_c);   // pos 511-t  (q2)

    ks_[t]       = (kg[ch * 512 + t]       * cs_a + sgn * kg[p * 512 + t]       * sn_a) * SC;
    ks_[t + 256] = (kg[ch * 512 + t + 256] * cs_b + sgn * kg[p * 512 + t + 256] * sn_b) * SC;
    vs_[t]       = vg[ch * 512 + t];
    vs_[t + 256] = vg[ch * 512 + t + 256];
    const float q1 = qg[ch * 512 + i1] * cs_a + sgn * qg[p * 512 + i1] * sn_a;
    const float q2 = qg[ch * 512 + i2] * cs_c + sgn * qg[p * 512 + i2] * sn_c;
    __syncthreads();

    float l1 = 0.f, a1 = 0.f, l2 = 0.f, a2 = 0.f;
    const int w64 = t & ~63;             // 64*w, wave-uniform

    // Phase 1a: dual query, unmasked
    #pragma unroll 2
    for (int j = 0; j < w64; j += 4) {
        const float4 kk = *(const float4*)&ks_[j];
        const float4 vv = *(const float4*)&vs_[j];
        float e;
        e = __builtin_amdgcn_exp2f(q1 * kk.x); l1 += e; a1 = fmaf(e, vv.x, a1);
        e = __builtin_amdgcn_exp2f(q2 * kk.x); l2 += e; a2 = fmaf(e, vv.x, a2);
        e = __builtin_amdgcn_exp2f(q1 * kk.y); l1 += e; a1 = fmaf(e, vv.y, a1);
        e = __builtin_amdgcn_exp2f(q2 * kk.y); l2 += e; a2 = fmaf(e, vv.y, a2);
        e = __builtin_amdgcn_exp2f(q1 * kk.z); l1 += e; a1 = fmaf(e, vv.z, a1);
        e = __builtin_amdgcn_exp2f(q2 * kk.z); l2 += e; a2 = fmaf(e, vv.z, a2);
        e = __builtin_amdgcn_exp2f(q1 * kk.w); l1 += e; a1 = fmaf(e, vv.w, a1);
        e = __builtin_amdgcn_exp2f(q2 * kk.w); l2 += e; a2 = fmaf(e, vv.w, a2);
    }
    // Phase 1b: q1 masked tail, q2 unmasked
    #pragma unroll 4
    for (int u = 0; u < 64; u += 4) {
        const int j = w64 + u;
        const float4 kk = *(const float4*)&ks_[j];
        const float4 vv = *(const float4*)&vs_[j];
        float e;
        e = (j + 0 <= i1) ? __builtin_amdgcn_exp2f(q1 * kk.x) : 0.f; l1 += e; a1 = fmaf(e, vv.x, a1);
        e = __builtin_amdgcn_exp2f(q2 * kk.x);                       l2 += e; a2 = fmaf(e, vv.x, a2);
        e = (j + 1 <= i1) ? __builtin_amdgcn_exp2f(q1 * kk.y) : 0.f; l1 += e; a1 = fmaf(e, vv.y, a1);
        e = __builtin_amdgcn_exp2f(q2 * kk.y);                       l2 += e; a2 = fmaf(e, vv.y, a2);
        e = (j + 2 <= i1) ? __builtin_amdgcn_exp2f(q1 * kk.z) : 0.f; l1 += e; a1 = fmaf(e, vv.z, a1);
        e = __builtin_amdgcn_exp2f(q2 * kk.z);                       l2 += e; a2 = fmaf(e, vv.z, a2);
        e = (j + 3 <= i1) ? __builtin_amdgcn_exp2f(q1 * kk.w) : 0.f; l1 += e; a1 = fmaf(e, vv.w, a1);
        e = __builtin_amdgcn_exp2f(q2 * kk.w);                       l2 += e; a2 = fmaf(e, vv.w, a2);
    }
    // Phase 2a: q2 only, unmasked
    const int jend2 = 448 - w64;
    #pragma unroll 2
    for (int j = w64 + 64; j < jend2; j += 4) {
        const float4 kk = *(const float4*)&ks_[j];
        const float4 vv = *(const float4*)&vs_[j];
        float e;
        e = __builtin_amdgcn_exp2f(q2 * kk.x); l2 += e; a2 = fmaf(e, vv.x, a2);
        e = __builtin_amdgcn_exp2f(q2 * kk.y); l2 += e; a2 = fmaf(e, vv.y, a2);
        e = __builtin_amdgcn_exp2f(q2 * kk.z); l2 += e; a2 = fmaf(e, vv.z, a2);
        e = __builtin_amdgcn_exp2f(q2 * kk.w); l2 += e; a2 = fmaf(e, vv.w, a2);
    }
    // Phase 2b: q2 masked tail
    #pragma unroll 4
    for (int u = 0; u < 64; u += 4) {
        const int j = jend2 + u;
        const float4 kk = *(const float4*)&ks_[j];
        const float4 vv = *(const float4*)&vs_[j];
        float e;
        e = (j + 0 <= i2) ? __builtin_amdgcn_exp2f(q2 * kk.x) : 0.f; l2 += e; a2 = fmaf(e, vv.x, a2);
        e = (j + 1 <= i2) ? __builtin_amdgcn_exp2f(q2 * kk.y) : 0.f; l2 += e; a2 = fmaf(e, vv.y, a2);
        e = (j + 2 <= i2) ? __builtin_amdgcn_exp2f(q2 * kk.z) : 0.f; l2 += e; a2 = fmaf(e, vv.z, a2);
        e = (j + 3 <= i2) ? __builtin_amdgcn_exp2f(q2 * kk.w) : 0.f; l2 += e; a2 = fmaf(e, vv.w, a2);
    }

    // Direct transposed bf16 output: [t][ch]. Scattered 2B stores (stride
    // 1024B across the wave) — only 262k stores total, stays in L2, and it
    // deletes the separate attT_cvt kernel + f32 att round-trip.
    attTb[i1 * 512 + ch] = f2bf(a1 / l1);
    attTb[i2 * 512 + ch] = f2bf(a2 / l2);
}

// ---------------------------------------------------------------------------
extern "C" void kernel_launch(void* const* d_in, const int* in_sizes, int n_in,
                              void* d_out, int out_size, void* d_ws, size_t ws_size,
                              hipStream_t stream)
{
    const float* x  = (const float*)d_in[0];
    const float* Wq = (const float*)d_in[1];
    const float* Wk = (const float*)d_in[2];
    const float* Wv = (const float*)d_in[3];
    const float* Wo = (const float*)d_in[4];
    float* out = (float*)d_out;

    unsigned short* Wallb = (unsigned short*)d_ws;        // 786432 bf16
    unsigned short* xb    = Wallb + 786432;               // 262144
    unsigned short* Wob   = xb + 262144;                  // 262144
    unsigned short* attTb = Wob + 262144;                 // 262144
    float* qkvf = (float*)(attTb + 262144);               // 786432 f32

    cvt_bf16<<<dim3(256, 5), 256, 0, stream>>>(x, Wq, Wk, Wv, Wo, Wallb, xb, Wob);
    // qkv: C[o'][t] = sum_d Wall[o'][d] * x[t][d]   (M=1536, N=512)
    gemm_bt<<<dim3(8, 24), 256, 0, stream>>>(Wallb, xb, qkvf);
    // fused RoPE + attention + transpose-to-bf16
    attn_rope<<<512, 256, 0, stream>>>(qkvf, attTb);
    // out: C[t][o] = sum_d attT[t][d] * Wo[o][d]    (M=512, N=512)
    gemm_bt<<<dim3(8, 8), 256, 0, stream>>>(attTb, Wob, out);
}

// Round 2
// 92.747 us; speedup vs baseline: 1.1214x; 1.0101x over previous
//
#include <hip/hip_runtime.h>
#include <math.h>

// ---------------------------------------------------------------------------
// Types for MFMA fragments (guide §3: bf16 16x16x32 -> 8 bf16 in, 4 f32 out)
// ---------------------------------------------------------------------------
typedef __attribute__((ext_vector_type(8))) short short8;
typedef __attribute__((ext_vector_type(4))) float floatx4;

__device__ __forceinline__ unsigned short f2bf(float f) {
    unsigned int u = __builtin_bit_cast(unsigned int, f);
    u += 0x7FFFu + ((u >> 16) & 1u);   // round-to-nearest-even
    return (unsigned short)(u >> 16);
}

// ---------------------------------------------------------------------------
// ws layout:
//   Wallb bf16 [1536][512]  (Wq rows 0-511, Wk 512-1023, Wv 1024-1535)
//   xb    bf16 [512][512]   (x, [t][d])
//   Wob   bf16 [512][512]   ([o][d])
//   attTb bf16 [512][512]   ([t][d])  <- written directly by attn_rope
//   qkvf  f32  [1536][512]  ([o'][t]; q rows 0-511, k 512-1023, v 1024-1535)
// ---------------------------------------------------------------------------

// ---------------------------------------------------------------------------
// Kernel 1: fp32 -> bf16 conversion for x, Wq, Wk, Wv, Wo (pure elementwise).
// grid (256, 5), block 256; each thread converts 4 elements.
// ---------------------------------------------------------------------------
__global__ __launch_bounds__(256) void cvt_bf16(
    const float* __restrict__ x,  const float* __restrict__ Wq,
    const float* __restrict__ Wk, const float* __restrict__ Wv,
    const float* __restrict__ Wo, unsigned short* __restrict__ Wallb,
    unsigned short* __restrict__ xb, unsigned short* __restrict__ Wob)
{
    const float* src; unsigned short* dst;
    switch (blockIdx.y) {
        case 0: src = Wq; dst = Wallb;          break;
        case 1: src = Wk; dst = Wallb + 262144; break;
        case 2: src = Wv; dst = Wallb + 524288; break;
        case 3: src = x;  dst = xb;             break;
        default: src = Wo; dst = Wob;           break;
    }
    const int i4 = (blockIdx.x * 256 + threadIdx.x) * 4;
    const float4 v = *(const float4*)(src + i4);
    ushort4 o;
    o.x = f2bf(v.x); o.y = f2bf(v.y); o.z = f2bf(v.z); o.w = f2bf(v.w);
    *(ushort4*)(dst + i4) = o;
}

// ---------------------------------------------------------------------------
// Kernel 2/4: bf16 MFMA GEMM, C[m][n] = sum_k A[m][k]*B[n][k] (both k-contig).
// K = 512 fixed, ldc = 512 fixed. Block 256 thr = 4 waves; 64x64 block tile;
// wave tile 32x32 = 2x2 mfma_f32_16x16x32_bf16 tiles.
//
// FULL-K-RESIDENT version: As[64][512] + Bs[64][512] = 128 KiB LDS (fits the
// 160 KiB CU budget; both launches run <=1 block/CU anyway, so the occupancy
// cost is zero). One glds width-16 covers exactly one full row (64 lanes x
// 16 B = 1024 B = 512 bf16), so 32 glds/wave stage the entire panel. Global
// load latency is paid ONCE (single vmcnt(0) + single barrier) instead of 8
// times; the whole 128-MFMA compute then runs with zero barriers and all
// operands LDS-resident. Bank conflicts avoided by pre-swizzling the per-lane
// GLOBAL source chunk (lane ^ (row&7), m173 pattern) and applying the same
// involution on the ds_read side (rule #21).
// ---------------------------------------------------------------------------
__global__ __launch_bounds__(256) void gemm_bt(
    const unsigned short* __restrict__ A,   // [M][512] bf16
    const unsigned short* __restrict__ B,   // [N][512] bf16
    float* __restrict__ C)                  // [M][512] f32
{
    __shared__ unsigned short As[64 * 512];
    __shared__ unsigned short Bs[64 * 512];

    const int tid  = threadIdx.x;
    const int lane = tid & 63;
    const int w    = tid >> 6;            // wave 0..3
    const int m0   = blockIdx.y * 64;
    const int n0   = blockIdx.x * 64;
    const int wm   = (w >> 1) * 32;
    const int wn   = (w & 1) * 32;

    floatx4 acc[2][2] = {{{0.f,0.f,0.f,0.f},{0.f,0.f,0.f,0.f}},
                         {{0.f,0.f,0.f,0.f},{0.f,0.f,0.f,0.f}}};

    const int quad = lane >> 4;
    const int l15  = lane & 15;

    // Stage: wave w loads rows [16w, 16w+16) of A and B, one glds per row.
    // LDS chunk l (lane l's 16 B) receives global chunk l^(row&7), so the
    // read side fetches global chunk c from LDS chunk c^(row&7).
    #pragma unroll
    for (int r = 0; r < 16; ++r) {
        const int row = w * 16 + r;
        const int col = (lane ^ (row & 7)) * 8;       // pre-swizzled, in bf16
        __builtin_amdgcn_global_load_lds(
            (const __attribute__((address_space(1))) void*)(A + (m0 + row) * 512 + col),
            (__attribute__((address_space(3))) void*)&As[row * 512],
            16, 0, 0);
        __builtin_amdgcn_global_load_lds(
            (const __attribute__((address_space(1))) void*)(B + (n0 + row) * 512 + col),
            (__attribute__((address_space(3))) void*)&Bs[row * 512],
            16, 0, 0);
    }

    asm volatile("s_waitcnt vmcnt(0)" ::: "memory");
    __builtin_amdgcn_s_barrier();
    __builtin_amdgcn_sched_barrier(0);   // rule 18: pin ds_reads below barrier

    #pragma unroll
    for (int kt = 0; kt < 8; ++kt) {
        #pragma unroll
        for (int ks = 0; ks < 2; ++ks) {
            const int cIdx = kt * 8 + ks * 4 + quad;    // 16B chunk 0..63
            short8 a[2], b[2];
            #pragma unroll
            for (int mt = 0; mt < 2; ++mt) {
                const int row = wm + mt * 16 + l15;
                a[mt] = *(const short8*)&As[row * 512 + ((cIdx ^ (row & 7)) * 8)];
            }
            #pragma unroll
            for (int nt = 0; nt < 2; ++nt) {
                const int row = wn + nt * 16 + l15;
                b[nt] = *(const short8*)&Bs[row * 512 + ((cIdx ^ (row & 7)) * 8)];
            }
            #pragma unroll
            for (int mt = 0; mt < 2; ++mt)
                #pragma unroll
                for (int nt = 0; nt < 2; ++nt)
                    acc[mt][nt] = __builtin_amdgcn_mfma_f32_16x16x32_bf16(
                        a[mt], b[nt], acc[mt][nt], 0, 0, 0);
        }
    }

    // C/D layout (m89-verified): row = quad*4 + reg, col = lane&15
    #pragma unroll
    for (int mt = 0; mt < 2; ++mt)
        #pragma unroll
        for (int nt = 0; nt < 2; ++nt) {
            const int grow = m0 + wm + mt * 16 + quad * 4;
            const int gcol = n0 + wn + nt * 16 + l15;
            #pragma unroll
            for (int r = 0; r < 4; ++r)
                C[(grow + r) * 512 + gcol] = acc[mt][nt][r];
        }
}

// ---------------------------------------------------------------------------
// Kernel 3: fused RoPE + per-channel scalar causal attention (fp32),
// writing the transposed bf16 attention output attTb[t][ch] directly.
//
// Block = one channel ch (512 blocks), 256 threads. Thread t owns TWO
// queries: i1 = t and i2 = 511 - t, so every wave's weighted work is the
// uniform 576 j-steps (no triangle imbalance, no fully-masked tail). Scale
// 1/8 AND log2(e) are folded into k so the inner loop is a raw v_exp_f32
// (exp2) — 4 VALU ops per (i,j) element.
//
// Phase structure (w = wave id 0..3, all bounds wave-uniform):
//   1a: j in [0, 64w)           : both queries, unmasked   (j <  i1 min)
//   1b: j in [64w, 64w+64)      : q1 masked (j<=i1), q2 unmasked (j<256<=i2)
//   2a: j in [64w+64, 448-64w)  : q2 only, unmasked        (j <  i2 min)
//   2b: j in [448-64w, 512-64w) : q2 masked (j<=i2)
// No max-subtraction: |q*k/8| <~ 3, exp cannot overflow; same math as ref.
// ---------------------------------------------------------------------------
__global__ __launch_bounds__(256) void attn_rope(
    const float* __restrict__ qkv, unsigned short* __restrict__ attTb)
{
    const int ch = blockIdx.x;
    const int t  = threadIdx.x;          // 0..255
    const int i1 = t;
    const int i2 = 511 - t;
    const int p  = ch ^ 256;
    const float sgn = (ch < 256) ? -1.f : 1.f;

    __shared__ float ks_[512];
    __shared__ float vs_[512];

    const float* __restrict__ qg = qkv;
    const float* __restrict__ kg = qkv + 262144;
    const float* __restrict__ vg = qkv + 524288;

    const float inv_freq = powf(10000.f, -(float)(ch & 31) * (1.f / 32.f));
    const float SC = 0.125f * 1.44269504088896f;  // 1/8 * log2(e) folded into k

    float sn_a, cs_a, sn_b, cs_b, sn_c, cs_c;
    sincosf((float)t * inv_freq,         &sn_a, &cs_a);   // pos t      (k + q1)
    sincosf((float)(t + 256) * inv_freq, &sn_b, &cs_b);   // pos t+256  (k)
    sincosf((float)i2 * inv_freq,        &sn_c, &cs_c);   // pos 511-t  (q2)

    ks_[t]       = (kg[ch * 512 + t]       * cs_a + sgn * kg[p * 512 + t]       * sn_a) * SC;
    ks_[t + 256] = (kg[ch * 512 + t + 256] * cs_b + sgn * kg[p * 512 + t + 256] * sn_b) * SC;
    vs_[t]       = vg[ch * 512 + t];
    vs_[t + 256] = vg[ch * 512 + t + 256];
    const float q1 = qg[ch * 512 + i1] * cs_a + sgn * qg[p * 512 + i1] * sn_a;
    const float q2 = qg[ch * 512 + i2] * cs_c + sgn * qg[p * 512 + i2] * sn_c;
    __syncthreads();

    float l1 = 0.f, a1 = 0.f, l2 = 0.f, a2 = 0.f;
    const int w64 = t & ~63;             // 64*w, wave-uniform

    // Phase 1a: dual query, unmasked
    #pragma unroll 2
    for (int j = 0; j < w64; j += 4) {
        const float4 kk = *(const float4*)&ks_[j];
        const float4 vv = *(const float4*)&vs_[j];
        float e;
        e = __builtin_amdgcn_exp2f(q1 * kk.x); l1 += e; a1 = fmaf(e, vv.x, a1);
        e = __builtin_amdgcn_exp2f(q2 * kk.x); l2 += e; a2 = fmaf(e, vv.x, a2);
        e = __builtin_amdgcn_exp2f(q1 * kk.y); l1 += e; a1 = fmaf(e, vv.y, a1);
        e = __builtin_amdgcn_exp2f(q2 * kk.y); l2 += e; a2 = fmaf(e, vv.y, a2);
        e = __builtin_amdgcn_exp2f(q1 * kk.z); l1 += e; a1 = fmaf(e, vv.z, a1);
        e = __builtin_amdgcn_exp2f(q2 * kk.z); l2 += e; a2 = fmaf(e, vv.z, a2);
        e = __builtin_amdgcn_exp2f(q1 * kk.w); l1 += e; a1 = fmaf(e, vv.w, a1);
        e = __builtin_amdgcn_exp2f(q2 * kk.w); l2 += e; a2 = fmaf(e, vv.w, a2);
    }
    // Phase 1b: q1 masked tail, q2 unmasked
    #pragma unroll 4
    for (int u = 0; u < 64; u += 4) {
        const int j = w64 + u;
        const float4 kk = *(const float4*)&ks_[j];
        const float4 vv = *(const float4*)&vs_[j];
        float e;
        e = (j + 0 <= i1) ? __builtin_amdgcn_exp2f(q1 * kk.x) : 0.f; l1 += e; a1 = fmaf(e, vv.x, a1);
        e = __builtin_amdgcn_exp2f(q2 * kk.x);                       l2 += e; a2 = fmaf(e, vv.x, a2);
        e = (j + 1 <= i1) ? __builtin_amdgcn_exp2f(q1 * kk.y) : 0.f; l1 += e; a1 = fmaf(e, vv.y, a1);
        e = __builtin_amdgcn_exp2f(q2 * kk.y);                       l2 += e; a2 = fmaf(e, vv.y, a2);
        e = (j + 2 <= i1) ? __builtin_amdgcn_exp2f(q1 * kk.z) : 0.f; l1 += e; a1 = fmaf(e, vv.z, a1);
        e = __builtin_amdgcn_exp2f(q2 * kk.z);                       l2 += e; a2 = fmaf(e, vv.z, a2);
        e = (j + 3 <= i1) ? __builtin_amdgcn_exp2f(q1 * kk.w) : 0.f; l1 += e; a1 = fmaf(e, vv.w, a1);
        e = __builtin_amdgcn_exp2f(q2 * kk.w);                       l2 += e; a2 = fmaf(e, vv.w, a2);
    }
    // Phase 2a: q2 only, unmasked
    const int jend2 = 448 - w64;
    #pragma unroll 2
    for (int j = w64 + 64; j < jend2; j += 4) {
        const float4 kk = *(const float4*)&ks_[j];
        const float4 vv = *(const float4*)&vs_[j];
        float e;
        e = __builtin_amdgcn_exp2f(q2 * kk.x); l2 += e; a2 = fmaf(e, vv.x, a2);
        e = __builtin_amdgcn_exp2f(q2 * kk.y); l2 += e; a2 = fmaf(e, vv.y, a2);
        e = __builtin_amdgcn_exp2f(q2 * kk.z); l2 += e; a2 = fmaf(e, vv.z, a2);
        e = __builtin_amdgcn_exp2f(q2 * kk.w); l2 += e; a2 = fmaf(e, vv.w, a2);
    }
    // Phase 2b: q2 masked tail
    #pragma unroll 4
    for (int u = 0; u < 64; u += 4) {
        const int j = jend2 + u;
        const float4 kk = *(const float4*)&ks_[j];
        const float4 vv = *(const float4*)&vs_[j];
        float e;
        e = (j + 0 <= i2) ? __builtin_amdgcn_exp2f(q2 * kk.x) : 0.f; l2 += e; a2 = fmaf(e, vv.x, a2);
        e = (j + 1 <= i2) ? __builtin_amdgcn_exp2f(q2 * kk.y) : 0.f; l2 += e; a2 = fmaf(e, vv.y, a2);
        e = (j + 2 <= i2) ? __builtin_amdgcn_exp2f(q2 * kk.z) : 0.f; l2 += e; a2 = fmaf(e, vv.z, a2);
        e = (j + 3 <= i2) ? __builtin_amdgcn_exp2f(q2 * kk.w) : 0.f; l2 += e; a2 = fmaf(e, vv.w, a2);
    }

    // Direct transposed bf16 output: [t][ch]. Scattered 2B stores — only
    // 262k stores total, stays in L2, deletes the separate transpose kernel.
    attTb[i1 * 512 + ch] = f2bf(a1 / l1);
    attTb[i2 * 512 + ch] = f2bf(a2 / l2);
}

// ---------------------------------------------------------------------------
extern "C" void kernel_launch(void* const* d_in, const int* in_sizes, int n_in,
                              void* d_out, int out_size, void* d_ws, size_t ws_size,
                              hipStream_t stream)
{
    const float* x  = (const float*)d_in[0];
    const float* Wq = (const float*)d_in[1];
    const float* Wk = (const float*)d_in[2];
    const float* Wv = (const float*)d_in[3];
    const float* Wo = (const float*)d_in[4];
    float* out = (float*)d_out;

    unsigned short* Wallb = (unsigned short*)d_ws;        // 786432 bf16
    unsigned short* xb    = Wallb + 786432;               // 262144
    unsigned short* Wob   = xb + 262144;                  // 262144
    unsigned short* attTb = Wob + 262144;                 // 262144
    float* qkvf = (float*)(attTb + 262144);               // 786432 f32

    cvt_bf16<<<dim3(256, 5), 256, 0, stream>>>(x, Wq, Wk, Wv, Wo, Wallb, xb, Wob);
    // qkv: C[o'][t] = sum_d Wall[o'][d] * x[t][d]   (M=1536, N=512)
    gemm_bt<<<dim3(8, 24), 256, 0, stream>>>(Wallb, xb, qkvf);
    // fused RoPE + attention + transpose-to-bf16
    attn_rope<<<512, 256, 0, stream>>>(qkvf, attTb);
    // out: C[t][o] = sum_d attT[t][d] * Wo[o][d]    (M=512, N=512)
    gemm_bt<<<dim3(8, 8), 256, 0, stream>>>(attTb, Wob, out);
}

// Round 3
// 92.542 us; speedup vs baseline: 1.1238x; 1.0022x over previous
//
#include <hip/hip_runtime.h>
#include <math.h>

// ---------------------------------------------------------------------------
// Types for MFMA fragments (guide §3: bf16 16x16x32 -> 8 bf16 in, 4 f32 out)
// ---------------------------------------------------------------------------
typedef __attribute__((ext_vector_type(8))) short short8;
typedef __attribute__((ext_vector_type(4))) float floatx4;

__device__ __forceinline__ unsigned short f2bf(float f) {
    unsigned int u = __builtin_bit_cast(unsigned int, f);
    u += 0x7FFFu + ((u >> 16) & 1u);   // round-to-nearest-even
    return (unsigned short)(u >> 16);
}

// ---------------------------------------------------------------------------
// ws layout (shrunk: conversion now fused into the GEMM staging phases):
//   attTb bf16 [512][512]   ([t][d])  <- written directly by attn_rope
//   qkvf  f32  [1536][512]  ([o'][t]; q rows 0-511, k 512-1023, v 1024-1535)
// ---------------------------------------------------------------------------

// Stage one 512-f32 row as swizzled bf16 into LDS: 2x float4 load ->
// 4x v_cvt_pk_bf16_f32 (RNE, identical to f2bf) -> 1x ds_write_b128.
// Write-side swizzle chunk = lane ^ (row&7); read side applies the same
// involution (rule #21: both-sides-or-neither).
__device__ __forceinline__ void stage_row_f32(
    const float* __restrict__ src, unsigned short* __restrict__ dst,
    int lane, int row)
{
    const float4 f0 = *(const float4*)(src + lane * 8);
    const float4 f1 = *(const float4*)(src + lane * 8 + 4);
    unsigned int p0, p1, p2, p3;
    asm("v_cvt_pk_bf16_f32 %0, %1, %2" : "=v"(p0) : "v"(f0.x), "v"(f0.y));
    asm("v_cvt_pk_bf16_f32 %0, %1, %2" : "=v"(p1) : "v"(f0.z), "v"(f0.w));
    asm("v_cvt_pk_bf16_f32 %0, %1, %2" : "=v"(p2) : "v"(f1.x), "v"(f1.y));
    asm("v_cvt_pk_bf16_f32 %0, %1, %2" : "=v"(p3) : "v"(f1.z), "v"(f1.w));
    uint4 pk; pk.x = p0; pk.y = p1; pk.z = p2; pk.w = p3;
    *(uint4*)&dst[(lane ^ (row & 7)) * 8] = pk;
}

// ---------------------------------------------------------------------------
// Kernel 1: QKV projection GEMM with fused f32->bf16 conversion.
// C[o'][t] = sum_d W[o'][d] * x[t][d];  M=1536 (Wq|Wk|Wv), N=512, K=512.
// Block 256 thr = 4 waves; 64x64 tile; wave tile 32x32 = 2x2 16x16x32 MFMAs.
// FULL-K-RESIDENT: As[64][512]+Bs[64][512] = 128 KiB (1 block/CU, fine).
// Both operands are f32 in HBM; staging converts in-register (cvt_pk) and
// ds_writes swizzled bf16 — the standalone cvt kernel is gone.
// Each 64-row panel lies entirely within one of Wq/Wk/Wv (24 = 3*8 panels).
// ---------------------------------------------------------------------------
__global__ __launch_bounds__(256) void gemm_qkv(
    const float* __restrict__ Wq, const float* __restrict__ Wk,
    const float* __restrict__ Wv, const float* __restrict__ x,
    float* __restrict__ C)                  // [1536][512] f32
{
    __shared__ unsigned short As[64 * 512];
    __shared__ unsigned short Bs[64 * 512];

    const int tid  = threadIdx.x;
    const int lane = tid & 63;
    const int w    = tid >> 6;            // wave 0..3
    const int m0   = blockIdx.y * 64;     // 0..1472
    const int n0   = blockIdx.x * 64;
    const int wm   = (w >> 1) * 32;
    const int wn   = (w & 1) * 32;

    const float* __restrict__ Aall =
        (m0 < 512) ? Wq : ((m0 < 1024) ? Wk : Wv);
    const float* __restrict__ Asrc = Aall + (m0 & 511) * 512;
    const float* __restrict__ Bsrc = x + n0 * 512;

    floatx4 acc[2][2] = {{{0.f,0.f,0.f,0.f},{0.f,0.f,0.f,0.f}},
                         {{0.f,0.f,0.f,0.f},{0.f,0.f,0.f,0.f}}};

    const int quad = lane >> 4;
    const int l15  = lane & 15;

    // Stage: wave w converts rows [16w, 16w+16) of A and B.
    #pragma unroll
    for (int r = 0; r < 16; ++r) {
        const int row = w * 16 + r;
        stage_row_f32(Asrc + row * 512, &As[row * 512], lane, row);
        stage_row_f32(Bsrc + row * 512, &Bs[row * 512], lane, row);
    }
    __syncthreads();
    __builtin_amdgcn_sched_barrier(0);

    #pragma unroll
    for (int kt = 0; kt < 8; ++kt) {
        #pragma unroll
        for (int ks = 0; ks < 2; ++ks) {
            const int cIdx = kt * 8 + ks * 4 + quad;    // 16B chunk 0..63
            short8 a[2], b[2];
            #pragma unroll
            for (int mt = 0; mt < 2; ++mt) {
                const int row = wm + mt * 16 + l15;
                a[mt] = *(const short8*)&As[row * 512 + ((cIdx ^ (row & 7)) * 8)];
            }
            #pragma unroll
            for (int nt = 0; nt < 2; ++nt) {
                const int row = wn + nt * 16 + l15;
                b[nt] = *(const short8*)&Bs[row * 512 + ((cIdx ^ (row & 7)) * 8)];
            }
            #pragma unroll
            for (int mt = 0; mt < 2; ++mt)
                #pragma unroll
                for (int nt = 0; nt < 2; ++nt)
                    acc[mt][nt] = __builtin_amdgcn_mfma_f32_16x16x32_bf16(
                        a[mt], b[nt], acc[mt][nt], 0, 0, 0);
        }
    }

    // C/D layout (m89-verified): row = quad*4 + reg, col = lane&15
    #pragma unroll
    for (int mt = 0; mt < 2; ++mt)
        #pragma unroll
        for (int nt = 0; nt < 2; ++nt) {
            const int grow = m0 + wm + mt * 16 + quad * 4;
            const int gcol = n0 + wn + nt * 16 + l15;
            #pragma unroll
            for (int r = 0; r < 4; ++r)
                C[(grow + r) * 512 + gcol] = acc[mt][nt][r];
        }
}

// ---------------------------------------------------------------------------
// Kernel 3: output projection GEMM, mixed staging.
// C[t][o] = sum_d attT[t][d] * Wo[o][d];  M=512, N=512, K=512.
// A (attTb) is already bf16 -> proven global_load_lds path (pre-swizzled
// global source, linear LDS dest). B (Wo) is f32 -> fused reg-cvt staging.
// glds for A issued FIRST so its latency overlaps B's load+cvt+ds_write.
// ---------------------------------------------------------------------------
__global__ __launch_bounds__(256) void gemm_out(
    const unsigned short* __restrict__ A,   // attTb [512][512] bf16
    const float* __restrict__ B,            // Wo    [512][512] f32
    float* __restrict__ C)                  // out   [512][512] f32
{
    __shared__ unsigned short As[64 * 512];
    __shared__ unsigned short Bs[64 * 512];

    const int tid  = threadIdx.x;
    const int lane = tid & 63;
    const int w    = tid >> 6;            // wave 0..3
    const int m0   = blockIdx.y * 64;     // t
    const int n0   = blockIdx.x * 64;     // o
    const int wm   = (w >> 1) * 32;
    const int wn   = (w & 1) * 32;

    floatx4 acc[2][2] = {{{0.f,0.f,0.f,0.f},{0.f,0.f,0.f,0.f}},
                         {{0.f,0.f,0.f,0.f},{0.f,0.f,0.f,0.f}}};

    const int quad = lane >> 4;
    const int l15  = lane & 15;

    // A: one glds width-16 per row covers the whole 512-bf16 row.
    #pragma unroll
    for (int r = 0; r < 16; ++r) {
        const int row = w * 16 + r;
        const int col = (lane ^ (row & 7)) * 8;       // pre-swizzled source
        __builtin_amdgcn_global_load_lds(
            (const __attribute__((address_space(1))) void*)(A + (m0 + row) * 512 + col),
            (__attribute__((address_space(3))) void*)&As[row * 512],
            16, 0, 0);
    }
    // B: reg-cvt staging (overlaps the glds latency above).
    #pragma unroll
    for (int r = 0; r < 16; ++r) {
        const int row = w * 16 + r;
        stage_row_f32(B + (n0 + row) * 512, &Bs[row * 512], lane, row);
    }
    __syncthreads();
    __builtin_amdgcn_sched_barrier(0);

    #pragma unroll
    for (int kt = 0; kt < 8; ++kt) {
        #pragma unroll
        for (int ks = 0; ks < 2; ++ks) {
            const int cIdx = kt * 8 + ks * 4 + quad;    // 16B chunk 0..63
            short8 a[2], b[2];
            #pragma unroll
            for (int mt = 0; mt < 2; ++mt) {
                const int row = wm + mt * 16 + l15;
                a[mt] = *(const short8*)&As[row * 512 + ((cIdx ^ (row & 7)) * 8)];
            }
            #pragma unroll
            for (int nt = 0; nt < 2; ++nt) {
                const int row = wn + nt * 16 + l15;
                b[nt] = *(const short8*)&Bs[row * 512 + ((cIdx ^ (row & 7)) * 8)];
            }
            #pragma unroll
            for (int mt = 0; mt < 2; ++mt)
                #pragma unroll
                for (int nt = 0; nt < 2; ++nt)
                    acc[mt][nt] = __builtin_amdgcn_mfma_f32_16x16x32_bf16(
                        a[mt], b[nt], acc[mt][nt], 0, 0, 0);
        }
    }

    // C/D layout (m89-verified): row = quad*4 + reg, col = lane&15
    #pragma unroll
    for (int mt = 0; mt < 2; ++mt)
        #pragma unroll
        for (int nt = 0; nt < 2; ++nt) {
            const int grow = m0 + wm + mt * 16 + quad * 4;
            const int gcol = n0 + wn + nt * 16 + l15;
            #pragma unroll
            for (int r = 0; r < 4; ++r)
                C[(grow + r) * 512 + gcol] = acc[mt][nt][r];
        }
}

// ---------------------------------------------------------------------------
// Kernel 2: fused RoPE + per-channel scalar causal attention (fp32),
// writing the transposed bf16 attention output attTb[t][ch] directly.
//
// Block = one channel ch (512 blocks), 256 threads. Thread t owns TWO
// queries: i1 = t and i2 = 511 - t, so every wave's weighted work is the
// uniform 576 j-steps (no triangle imbalance, no fully-masked tail). Scale
// 1/8 AND log2(e) are folded into k so the inner loop is a raw v_exp_f32
// (exp2) — 4 VALU ops per (i,j) element.
//
// Phase structure (w = wave id 0..3, all bounds wave-uniform):
//   1a: j in [0, 64w)           : both queries, unmasked   (j <  i1 min)
//   1b: j in [64w, 64w+64)      : q1 masked (j<=i1), q2 unmasked (j<256<=i2)
//   2a: j in [64w+64, 448-64w)  : q2 only, unmasked        (j <  i2 min)
//   2b: j in [448-64w, 512-64w) : q2 masked (j<=i2)
// No max-subtraction: |q*k/8| <~ 3, exp cannot overflow; same math as ref.
// ---------------------------------------------------------------------------
__global__ __launch_bounds__(256) void attn_rope(
    const float* __restrict__ qkv, unsigned short* __restrict__ attTb)
{
    const int ch = blockIdx.x;
    const int t  = threadIdx.x;          // 0..255
    const int i1 = t;
    const int i2 = 511 - t;
    const int p  = ch ^ 256;
    const float sgn = (ch < 256) ? -1.f : 1.f;

    __shared__ float ks_[512];
    __shared__ float vs_[512];

    const float* __restrict__ qg = qkv;
    const float* __restrict__ kg = qkv + 262144;
    const float* __restrict__ vg = qkv + 524288;

    const float inv_freq = powf(10000.f, -(float)(ch & 31) * (1.f / 32.f));
    const float SC = 0.125f * 1.44269504088896f;  // 1/8 * log2(e) folded into k

    float sn_a, cs_a, sn_b, cs_b, sn_c, cs_c;
    sincosf((float)t * inv_freq,         &sn_a, &cs_a);   // pos t      (k + q1)
    sincosf((float)(t + 256) * inv_freq, &sn_b, &cs_b);   // pos t+256  (k)
    sincosf((float)i2 * inv_freq,        &sn_c, &cs_c);   // pos 511-t  (q2)

    ks_[t]       = (kg[ch * 512 + t]       * cs_a + sgn * kg[p * 512 + t]       * sn_a) * SC;
    ks_[t + 256] = (kg[ch * 512 + t + 256] * cs_b + sgn * kg[p * 512 + t + 256] * sn_b) * SC;
    vs_[t]       = vg[ch * 512 + t];
    vs_[t + 256] = vg[ch * 512 + t + 256];
    const float q1 = qg[ch * 512 + i1] * cs_a + sgn * qg[p * 512 + i1] * sn_a;
    const float q2 = qg[ch * 512 + i2] * cs_c + sgn * qg[p * 512 + i2] * sn_c;
    __syncthreads();

    float l1 = 0.f, a1 = 0.f, l2 = 0.f, a2 = 0.f;
    const int w64 = t & ~63;             // 64*w, wave-uniform

    // Phase 1a: dual query, unmasked
    #pragma unroll 2
    for (int j = 0; j < w64; j += 4) {
        const float4 kk = *(const float4*)&ks_[j];
        const float4 vv = *(const float4*)&vs_[j];
        float e;
        e = __builtin_amdgcn_exp2f(q1 * kk.x); l1 += e; a1 = fmaf(e, vv.x, a1);
        e = __builtin_amdgcn_exp2f(q2 * kk.x); l2 += e; a2 = fmaf(e, vv.x, a2);
        e = __builtin_amdgcn_exp2f(q1 * kk.y); l1 += e; a1 = fmaf(e, vv.y, a1);
        e = __builtin_amdgcn_exp2f(q2 * kk.y); l2 += e; a2 = fmaf(e, vv.y, a2);
        e = __builtin_amdgcn_exp2f(q1 * kk.z); l1 += e; a1 = fmaf(e, vv.z, a1);
        e = __builtin_amdgcn_exp2f(q2 * kk.z); l2 += e; a2 = fmaf(e, vv.z, a2);
        e = __builtin_amdgcn_exp2f(q1 * kk.w); l1 += e; a1 = fmaf(e, vv.w, a1);
        e = __builtin_amdgcn_exp2f(q2 * kk.w); l2 += e; a2 = fmaf(e, vv.w, a2);
    }
    // Phase 1b: q1 masked tail, q2 unmasked
    #pragma unroll 4
    for (int u = 0; u < 64; u += 4) {
        const int j = w64 + u;
        const float4 kk = *(const float4*)&ks_[j];
        const float4 vv = *(const float4*)&vs_[j];
        float e;
        e = (j + 0 <= i1) ? __builtin_amdgcn_exp2f(q1 * kk.x) : 0.f; l1 += e; a1 = fmaf(e, vv.x, a1);
        e = __builtin_amdgcn_exp2f(q2 * kk.x);                       l2 += e; a2 = fmaf(e, vv.x, a2);
        e = (j + 1 <= i1) ? __builtin_amdgcn_exp2f(q1 * kk.y) : 0.f; l1 += e; a1 = fmaf(e, vv.y, a1);
        e = __builtin_amdgcn_exp2f(q2 * kk.y);                       l2 += e; a2 = fmaf(e, vv.y, a2);
        e = (j + 2 <= i1) ? __builtin_amdgcn_exp2f(q1 * kk.z) : 0.f; l1 += e; a1 = fmaf(e, vv.z, a1);
        e = __builtin_amdgcn_exp2f(q2 * kk.z);                       l2 += e; a2 = fmaf(e, vv.z, a2);
        e = (j + 3 <= i1) ? __builtin_amdgcn_exp2f(q1 * kk.w) : 0.f; l1 += e; a1 = fmaf(e, vv.w, a1);
        e = __builtin_amdgcn_exp2f(q2 * kk.w);                       l2 += e; a2 = fmaf(e, vv.w, a2);
    }
    // Phase 2a: q2 only, unmasked
    const int jend2 = 448 - w64;
    #pragma unroll 2
    for (int j = w64 + 64; j < jend2; j += 4) {
        const float4 kk = *(const float4*)&ks_[j];
        const float4 vv = *(const float4*)&vs_[j];
        float e;
        e = __builtin_amdgcn_exp2f(q2 * kk.x); l2 += e; a2 = fmaf(e, vv.x, a2);
        e = __builtin_amdgcn_exp2f(q2 * kk.y); l2 += e; a2 = fmaf(e, vv.y, a2);
        e = __builtin_amdgcn_exp2f(q2 * kk.z); l2 += e; a2 = fmaf(e, vv.z, a2);
        e = __builtin_amdgcn_exp2f(q2 * kk.w); l2 += e; a2 = fmaf(e, vv.w, a2);
    }
    // Phase 2b: q2 masked tail
    #pragma unroll 4
    for (int u = 0; u < 64; u += 4) {
        const int j = jend2 + u;
        const float4 kk = *(const float4*)&ks_[j];
        const float4 vv = *(const float4*)&vs_[j];
        float e;
        e = (j + 0 <= i2) ? __builtin_amdgcn_exp2f(q2 * kk.x) : 0.f; l2 += e; a2 = fmaf(e, vv.x, a2);
        e = (j + 1 <= i2) ? __builtin_amdgcn_exp2f(q2 * kk.y) : 0.f; l2 += e; a2 = fmaf(e, vv.y, a2);
        e = (j + 2 <= i2) ? __builtin_amdgcn_exp2f(q2 * kk.z) : 0.f; l2 += e; a2 = fmaf(e, vv.z, a2);
        e = (j + 3 <= i2) ? __builtin_amdgcn_exp2f(q2 * kk.w) : 0.f; l2 += e; a2 = fmaf(e, vv.w, a2);
    }

    // Direct transposed bf16 output: [t][ch]. Scattered 2B stores — only
    // 262k stores total, stays in L2, deletes the separate transpose kernel.
    attTb[i1 * 512 + ch] = f2bf(a1 / l1);
    attTb[i2 * 512 + ch] = f2bf(a2 / l2);
}

// ---------------------------------------------------------------------------
extern "C" void kernel_launch(void* const* d_in, const int* in_sizes, int n_in,
                              void* d_out, int out_size, void* d_ws, size_t ws_size,
                              hipStream_t stream)
{
    const float* x  = (const float*)d_in[0];
    const float* Wq = (const float*)d_in[1];
    const float* Wk = (const float*)d_in[2];
    const float* Wv = (const float*)d_in[3];
    const float* Wo = (const float*)d_in[4];
    float* out = (float*)d_out;

    unsigned short* attTb = (unsigned short*)d_ws;        // 262144 bf16
    float* qkvf = (float*)(attTb + 262144);               // 786432 f32

    // qkv: C[o'][t] = sum_d W[o'][d] * x[t][d]   (M=1536, N=512), fused cvt
    gemm_qkv<<<dim3(8, 24), 256, 0, stream>>>(Wq, Wk, Wv, x, qkvf);
    // fused RoPE + attention + transpose-to-bf16
    attn_rope<<<512, 256, 0, stream>>>(qkvf, attTb);
    // out: C[t][o] = sum_d attT[t][d] * Wo[o][d] (M=512, N=512), fused cvt
    gemm_out<<<dim3(8, 8), 256, 0, stream>>>(attTb, Wo, out);
}